// Round 2
// baseline (234.051 us; speedup 1.0000x reference)
//
#include <hip/hip_runtime.h>
#include <math.h>

// PCEN: out = (x / (smooth + eps)^alpha + delta)^r - delta^r
// smooth[0]=x[0]; smooth[t] = (1-S)*smooth[t-1] + S*x[t]
// x: [64,128,4096] fp32 -> 8192 rows of T=4096.

#define T_LEN 4096
#define BLOCK 256
#define PER   16   // elements per thread: 256*16 = 4096

__global__ __launch_bounds__(BLOCK) void pcen_kernel(const float* __restrict__ x,
                                                     float* __restrict__ out) {
    constexpr float A_COEF = 0.975f;   // 1 - S
    constexpr float S_COEF = 0.025f;   // S
    constexpr float ALPHA  = 0.98f;
    constexpr float EPS    = 1e-6f;
    constexpr float DELTA  = 2.0f;
    constexpr float SQRT_DELTA = 1.4142135623730951f;

    const int row = blockIdx.x;
    const float* __restrict__ xr  = x   + (size_t)row * T_LEN;
    float* __restrict__       orr = out + (size_t)row * T_LEN;

    const int tid  = threadIdx.x;
    const int base = tid * PER;

    // ---- load 16 contiguous elements (4x float4), keep in registers ----
    float xv[PER];
    const float4* xr4 = (const float4*)(xr + base);
#pragma unroll
    for (int i = 0; i < 4; ++i) {
        float4 v = xr4[i];
        xv[4*i+0] = v.x; xv[4*i+1] = v.y; xv[4*i+2] = v.z; xv[4*i+3] = v.w;
    }

    // ---- local affine composition over the 16 elements ----
    // segment map: y_out = A*y_in + B  (applied in increasing t)
    float A = 1.0f, B = 0.0f;
#pragma unroll
    for (int i = 0; i < PER; ++i) {
        float a = A_COEF, b = S_COEF * xv[i];
        if (base + i == 0) { a = 0.0f; b = xv[i]; }  // t==0: smooth = x[0]
        A = a * A;
        B = fmaf(a, B, b);
    }

    // ---- inclusive scan of affine pairs within the 64-lane wave ----
    const int lane = tid & 63;
#pragma unroll
    for (int off = 1; off < 64; off <<= 1) {
        float Au = __shfl_up(A, off);
        float Bu = __shfl_up(B, off);
        if (lane >= off) {
            B = fmaf(A, Bu, B);   // (A,B) ∘ (Au,Bu)
            A = A * Au;
        }
    }

    // ---- cross-wave combine (4 waves) ----
    __shared__ float wA[BLOCK / 64], wB[BLOCK / 64];
    const int wid = tid >> 6;
    if (lane == 63) { wA[wid] = A; wB[wid] = B; }
    __syncthreads();

    // exclusive-within-wave = inclusive shifted down by one lane
    float Aex = __shfl_up(A, 1);
    float Bex = __shfl_up(B, 1);
    if (lane == 0) { Aex = 1.0f; Bex = 0.0f; }

    // exclusive wave prefix: compose totals of waves 0..wid-1 in order
    float WA = 1.0f, WB = 0.0f;
    for (int w = 0; w < wid; ++w) {
        WB = fmaf(wA[w], WB, wB[w]);
        WA = wA[w] * WA;
    }

    // smooth value entering this thread's segment (y_init irrelevant: t==0 map has a=0)
    float y = fmaf(Aex, WB, Bex);

    // ---- replay segment: sequential EMA + pointwise PCEN ----
    float ov[PER];
#pragma unroll
    for (int i = 0; i < PER; ++i) {
        if (base + i == 0) y = xv[i];
        else               y = fmaf(A_COEF, y, S_COEF * xv[i]);
        // (smooth+eps)^(-alpha) via device exp2/log2 (v_exp_f32 / v_log_f32)
        float p = __builtin_exp2f(-ALPHA * __builtin_log2f(y + EPS));
        ov[i] = sqrtf(fmaf(xv[i], p, DELTA)) - SQRT_DELTA;
    }

    float4* o4 = (float4*)(orr + base);
#pragma unroll
    for (int i = 0; i < 4; ++i) {
        float4 v;
        v.x = ov[4*i+0]; v.y = ov[4*i+1]; v.z = ov[4*i+2]; v.w = ov[4*i+3];
        o4[i] = v;
    }
}

extern "C" void kernel_launch(void* const* d_in, const int* in_sizes, int n_in,
                              void* d_out, int out_size, void* d_ws, size_t ws_size,
                              hipStream_t stream) {
    const float* x = (const float*)d_in[0];
    float* out = (float*)d_out;
    const int rows = in_sizes[0] / T_LEN;  // 64*128 = 8192
    pcen_kernel<<<rows, BLOCK, 0, stream>>>(x, out);
}

// Round 3
// 223.457 us; speedup vs baseline: 1.0474x; 1.0474x over previous
//
#include <hip/hip_runtime.h>
#include <math.h>

// PCEN: out = (x / (smooth + eps)^alpha + delta)^r - delta^r
// smooth[0]=x[0]; smooth[t] = (1-S)*smooth[t-1] + S*x[t]
// x: [64,128,4096] fp32 -> 8192 rows of T=4096.
//
// One block per row. BLOCK=1024 threads x PER=4 elements: each thread's
// float4 load/store is lane-contiguous (perfect coalescing, 1KB/wave-instr).
// Recurrence parallelized as an affine-map scan: wave shfl scan + 16-entry
// LDS cross-wave combine. Transcendentals use raw v_log/v_exp/v_sqrt
// (inputs are in safe range: y+eps in [1e-6, ~1]).

#define T_LEN 4096
#define BLOCK 1024
#define PER   4    // 1024*4 = 4096
#define NWAVE (BLOCK / 64)

__global__ __launch_bounds__(BLOCK) void pcen_kernel(const float* __restrict__ x,
                                                     float* __restrict__ out) {
    constexpr float A_COEF = 0.975f;   // 1 - S
    constexpr float S_COEF = 0.025f;   // S
    constexpr float ALPHA  = 0.98f;
    constexpr float EPS    = 1e-6f;
    constexpr float DELTA  = 2.0f;
    constexpr float SQRT_DELTA = 1.4142135623730951f;

    const int row = blockIdx.x;
    const float* __restrict__ xr  = x   + (size_t)row * T_LEN;
    float* __restrict__       orr = out + (size_t)row * T_LEN;

    const int tid  = threadIdx.x;
    const int base = tid * PER;

    // ---- coalesced load: one float4 per thread ----
    float xv[PER];
    {
        float4 v = *(const float4*)(xr + base);
        xv[0] = v.x; xv[1] = v.y; xv[2] = v.z; xv[3] = v.w;
    }

    // ---- local affine composition over 4 elements ----
    // segment map: y_out = A*y_in + B  (applied in increasing t)
    float A, B;
    if (tid == 0) {
        // t==0: smooth = x[0] (absorbing map), then 3 EMA steps
        A = 0.0f; B = xv[0];
        for (int i = 1; i < PER; ++i) { B = fmaf(A_COEF, B, S_COEF * xv[i]); }
    } else {
        A = A_COEF; B = S_COEF * xv[0];
#pragma unroll
        for (int i = 1; i < PER; ++i) {
            B = fmaf(A_COEF, B, S_COEF * xv[i]);
            A = A * A_COEF;
        }
    }

    // ---- inclusive scan of affine pairs within the 64-lane wave ----
    const int lane = tid & 63;
#pragma unroll
    for (int off = 1; off < 64; off <<= 1) {
        float Au = __shfl_up(A, off);
        float Bu = __shfl_up(B, off);
        if (lane >= off) {
            B = fmaf(A, Bu, B);   // (A,B) ∘ (Au,Bu)
            A = A * Au;
        }
    }

    // ---- cross-wave combine (16 waves) ----
    __shared__ float wA[NWAVE], wB[NWAVE];
    const int wid = tid >> 6;
    if (lane == 63) { wA[wid] = A; wB[wid] = B; }
    __syncthreads();

    // exclusive-within-wave = inclusive shifted down one lane
    float Aex = __shfl_up(A, 1);
    float Bex = __shfl_up(B, 1);
    if (lane == 0) { Aex = 1.0f; Bex = 0.0f; }

    // exclusive wave prefix: compose totals of waves 0..wid-1 in order
    float WB = 0.0f;
    for (int w = 0; w < wid; ++w) {
        WB = fmaf(wA[w], WB, wB[w]);
    }

    // smooth value entering this thread's segment
    // (initial-y irrelevant: the t==0 map has A=0, making the row exact)
    float y = fmaf(Aex, WB, Bex);

    // ---- replay segment: sequential EMA + pointwise PCEN ----
    float ov[PER];
#pragma unroll
    for (int i = 0; i < PER; ++i) {
        if (tid == 0 && i == 0) y = xv[0];
        else                    y = fmaf(A_COEF, y, S_COEF * xv[i]);
        // (smooth+eps)^(-alpha) via raw v_log_f32 / v_exp_f32 (safe input range)
        float p = __builtin_amdgcn_exp2f(-ALPHA * __builtin_amdgcn_logf(y + EPS));
        ov[i] = __builtin_amdgcn_sqrtf(fmaf(xv[i], p, DELTA)) - SQRT_DELTA;
    }

    // ---- coalesced store ----
    float4 v;
    v.x = ov[0]; v.y = ov[1]; v.z = ov[2]; v.w = ov[3];
    *(float4*)(orr + base) = v;
}

extern "C" void kernel_launch(void* const* d_in, const int* in_sizes, int n_in,
                              void* d_out, int out_size, void* d_ws, size_t ws_size,
                              hipStream_t stream) {
    const float* x = (const float*)d_in[0];
    float* out = (float*)d_out;
    const int rows = in_sizes[0] / T_LEN;  // 64*128 = 8192
    pcen_kernel<<<rows, BLOCK, 0, stream>>>(x, out);
}